// Round 3
// baseline (2370.450 us; speedup 1.0000x reference)
//
#include <hip/hip_runtime.h>
#include <hip/hip_bf16.h>

#define NNODES 50000
#define NEDGES 400000
#define NGRAPH 50

// ---------------- CSR build ----------------

__global__ void count_kernel(const int* __restrict__ dst, int* __restrict__ cnt, int E) {
    int e = blockIdx.x * 256 + threadIdx.x;
    if (e < E) atomicAdd(&cnt[dst[e]], 1);
}

__global__ void dinv_kernel(const int* __restrict__ cnt, float* __restrict__ dinv, int N) {
    int i = blockIdx.x * 256 + threadIdx.x;
    if (i < N) dinv[i] = rsqrtf((float)cnt[i] + 1.0f);
}

// single-block exclusive scan: row_ptr[0]=0, row_ptr[i+1]=sum cnt[0..i]
__global__ void scan_kernel(const int* __restrict__ cnt, int* __restrict__ row_ptr, int N) {
    __shared__ int sm[1024];
    __shared__ int carry;
    int t = threadIdx.x;
    if (t == 0) { carry = 0; row_ptr[0] = 0; }
    __syncthreads();
    for (int base = 0; base < N; base += 1024) {
        int i = base + t;
        int v = (i < N) ? cnt[i] : 0;
        sm[t] = v;
        __syncthreads();
        for (int off = 1; off < 1024; off <<= 1) {
            int x = (t >= off) ? sm[t - off] : 0;
            __syncthreads();
            sm[t] += x;
            __syncthreads();
        }
        int total = sm[1023];
        if (i < N) row_ptr[i + 1] = carry + sm[t];
        __syncthreads();
        if (t == 0) carry += total;
        __syncthreads();
    }
}

__global__ void fill_kernel(const int* __restrict__ src, const int* __restrict__ dst,
                            const int* __restrict__ row_ptr, int* __restrict__ fill,
                            const float* __restrict__ dinv,
                            int* __restrict__ col, float* __restrict__ ew, int E) {
    int e = blockIdx.x * 256 + threadIdx.x;
    if (e < E) {
        int s = src[e], d = dst[e];
        int pos = row_ptr[d] + atomicAdd(&fill[d], 1);
        col[pos] = s;
        ew[pos] = dinv[s] * dinv[d];
    }
}

__global__ void countb_kernel(const int* __restrict__ batch, int* __restrict__ cntB, int N) {
    int i = blockIdx.x * 256 + threadIdx.x;
    if (i < N) atomicAdd(&cntB[batch[i]], 1);
}

// ---------------- dense transform: Y = [relu](X @ W [+ b]) ----------------
// COUT <= 256. rows per block = RT * (256/COUT).

template <int CIN, int COUT, int RT, bool PR>
__global__ void transform_kernel(const float* __restrict__ X, const float* __restrict__ W,
                                 const float* __restrict__ bias, float* __restrict__ Y, int N) {
    constexpr int RPB = RT * (256 / COUT);
    __shared__ float Ws[CIN * COUT];
    __shared__ float ps[RPB * CIN];
    int t = threadIdx.x;
    for (int i = t; i < CIN * COUT; i += 256) Ws[i] = W[i];
    int row0 = blockIdx.x * RPB;
    for (int i = t; i < RPB * CIN; i += 256) {
        int r = row0 + i / CIN;
        ps[i] = (r < N) ? X[r * CIN + (i % CIN)] : 0.f;
    }
    __syncthreads();
    int j = t % COUT;
    int lb = (t / COUT) * RT;
    float acc[RT];
    float bv = 0.f;
    if constexpr (PR) bv = bias[j];
    #pragma unroll
    for (int r = 0; r < RT; ++r) acc[r] = bv;
    #pragma unroll
    for (int k = 0; k < CIN; ++k) {
        float w = Ws[k * COUT + j];
        #pragma unroll
        for (int r = 0; r < RT; ++r) acc[r] += ps[(lb + r) * CIN + k] * w;
    }
    #pragma unroll
    for (int r = 0; r < RT; ++r) {
        int row = row0 + lb + r;
        if (row < N) {
            float v = acc[r];
            if constexpr (PR) v = fmaxf(v, 0.f);
            Y[row * COUT + j] = v;
        }
    }
}

// ---------------- propagation: xout = Ahat xin  [+bias, relu] ----------------
// pull-style over CSR(dst); C channels, 256/C nodes per block.

template <int C, bool PR>
__global__ void propagate_kernel(const float* __restrict__ xin, float* __restrict__ xout,
                                 const int* __restrict__ row_ptr, const int* __restrict__ col,
                                 const float* __restrict__ ew, const float* __restrict__ dinv,
                                 const float* __restrict__ bias, int N) {
    constexpr int NPB = 256 / C;
    int t = threadIdx.x;
    int node = blockIdx.x * NPB + t / C;
    int ch = t % C;
    if (node >= N) return;
    float di = dinv[node];
    float acc = xin[node * C + ch] * di * di;   // self-loop term
    int e0 = row_ptr[node], e1 = row_ptr[node + 1];
    for (int e = e0; e < e1; ++e) {
        int s = col[e];
        float w = ew[e];
        acc += xin[s * C + ch] * w;
    }
    if constexpr (PR) acc = fmaxf(acc + bias[ch], 0.f);
    xout[node * C + ch] = acc;
}

// ---------------- layer 5 GEMM (N,256)x(256,512) + bias + relu + mean-pool ----------------
// 128x64 tile, K-step 16, 256 threads, 8x4 microtile. Pool fused via LDS reduction
// (batch is sorted; per-block uniform fast path, atomic fallback at graph boundaries).

__global__ __launch_bounds__(256) void gemm5_pool(const float* __restrict__ A, const float* __restrict__ W,
                                                  const float* __restrict__ bias, const int* __restrict__ batch,
                                                  float* __restrict__ out, int N) {
    __shared__ float As[16][128];
    __shared__ float Bs[16][64];
    __shared__ float red[16][64];
    int t = threadIdx.x;
    int tx = t % 16, ty = t / 16;
    int row0 = blockIdx.x * 128;
    int col0 = blockIdx.y * 64;
    float acc[8][4];
    #pragma unroll
    for (int i = 0; i < 8; ++i)
        #pragma unroll
        for (int j = 0; j < 4; ++j) acc[i][j] = 0.f;

    for (int kc = 0; kc < 256; kc += 16) {
        #pragma unroll
        for (int it = 0; it < 2; ++it) {
            int idx = t + it * 256;        // 0..511
            int row = idx / 4;             // 0..127
            int kq = (idx % 4) * 4;
            int gr = row0 + row; if (gr > N - 1) gr = N - 1;
            const float4 v = *reinterpret_cast<const float4*>(&A[gr * 256 + kc + kq]);
            As[kq + 0][row] = v.x; As[kq + 1][row] = v.y;
            As[kq + 2][row] = v.z; As[kq + 3][row] = v.w;
        }
        {
            int kk = t / 16;
            int c4 = (t % 16) * 4;
            const float4 v = *reinterpret_cast<const float4*>(&W[(kc + kk) * 512 + col0 + c4]);
            *reinterpret_cast<float4*>(&Bs[kk][c4]) = v;
        }
        __syncthreads();
        #pragma unroll
        for (int kk = 0; kk < 16; ++kk) {
            float aL[8], bL[4];
            #pragma unroll
            for (int i = 0; i < 8; ++i) aL[i] = As[kk][ty + 16 * i];
            #pragma unroll
            for (int j = 0; j < 4; ++j) bL[j] = Bs[kk][tx + 16 * j];
            #pragma unroll
            for (int i = 0; i < 8; ++i)
                #pragma unroll
                for (int j = 0; j < 4; ++j) acc[i][j] += aL[i] * bL[j];
        }
        __syncthreads();
    }

    #pragma unroll
    for (int j = 0; j < 4; ++j) {
        float bv = bias[col0 + tx + 16 * j];
        #pragma unroll
        for (int i = 0; i < 8; ++i) acc[i][j] = fmaxf(acc[i][j] + bv, 0.f);
    }

    int rlast = row0 + 127; if (rlast > N - 1) rlast = N - 1;
    int b0 = batch[row0];
    int b1 = batch[rlast];
    if (b0 == b1) {
        #pragma unroll
        for (int j = 0; j < 4; ++j) {
            float p = 0.f;
            #pragma unroll
            for (int i = 0; i < 8; ++i) {
                int r = row0 + ty + 16 * i;
                if (r < N) p += acc[i][j];
            }
            red[ty][tx + 16 * j] = p;
        }
        __syncthreads();
        if (t < 64) {
            float s = 0.f;
            #pragma unroll
            for (int yy = 0; yy < 16; ++yy) s += red[yy][t];
            atomicAdd(&out[b0 * 512 + col0 + t], s);
        }
    } else {
        #pragma unroll
        for (int i = 0; i < 8; ++i) {
            int r = row0 + ty + 16 * i;
            if (r < N) {
                int bb = batch[r];
                #pragma unroll
                for (int j = 0; j < 4; ++j)
                    atomicAdd(&out[bb * 512 + col0 + tx + 16 * j], acc[i][j]);
            }
        }
    }
}

__global__ void divide_kernel(float* __restrict__ out, const int* __restrict__ cntB, int total) {
    int i = blockIdx.x * 256 + threadIdx.x;
    if (i < total) out[i] /= fmaxf((float)cntB[i >> 9], 1.f);
}

// ---------------- launch ----------------

extern "C" void kernel_launch(void* const* d_in, const int* in_sizes, int n_in,
                              void* d_out, int out_size, void* d_ws, size_t ws_size,
                              hipStream_t stream) {
    const float* x   = (const float*)d_in[0];
    const int* ei    = (const int*)d_in[1];
    const int* batch = (const int*)d_in[2];
    const float* W1 = (const float*)d_in[3];  const float* b1 = (const float*)d_in[4];
    const float* W2 = (const float*)d_in[5];  const float* b2 = (const float*)d_in[6];
    const float* W3 = (const float*)d_in[7];  const float* b3 = (const float*)d_in[8];
    const float* W4 = (const float*)d_in[9];  const float* b4 = (const float*)d_in[10];
    const float* W5 = (const float*)d_in[11]; const float* b5 = (const float*)d_in[12];
    float* out = (float*)d_out;

    const int N = NNODES, E = NEDGES;
    const int* src = ei;
    const int* dst = ei + E;

    char* ws = (char*)d_ws;
    size_t off = 0;
    auto alloc = [&](size_t bytes) {
        void* p = ws + off;
        off += (bytes + 255) & ~size_t(255);
        return p;
    };
    float* bufA   = (float*)alloc(sizeof(float) * size_t(N) * 256);
    float* bufB   = (float*)alloc(sizeof(float) * size_t(N) * 256);
    int* cnt      = (int*)alloc(sizeof(int) * N);
    int* fill     = (int*)alloc(sizeof(int) * N);
    int* row_ptr  = (int*)alloc(sizeof(int) * (N + 1));
    int* col      = (int*)alloc(sizeof(int) * E);
    float* ew     = (float*)alloc(sizeof(float) * E);
    float* dinv   = (float*)alloc(sizeof(float) * N);
    int* cntB     = (int*)alloc(sizeof(int) * NGRAPH);

    hipMemsetAsync(cnt, 0, sizeof(int) * N, stream);
    hipMemsetAsync(fill, 0, sizeof(int) * N, stream);
    hipMemsetAsync(cntB, 0, sizeof(int) * NGRAPH, stream);
    hipMemsetAsync(out, 0, sizeof(float) * out_size, stream);

    count_kernel<<<(E + 255) / 256, 256, 0, stream>>>(dst, cnt, E);
    dinv_kernel<<<(N + 255) / 256, 256, 0, stream>>>(cnt, dinv, N);
    scan_kernel<<<1, 1024, 0, stream>>>(cnt, row_ptr, N);
    fill_kernel<<<(E + 255) / 256, 256, 0, stream>>>(src, dst, row_ptr, fill, dinv, col, ew, E);
    countb_kernel<<<(N + 255) / 256, 256, 0, stream>>>(batch, cntB, N);

    // L1: transform-first (32 -> 8), then propagate (+b1, relu)
    transform_kernel<32, 8, 1, false><<<(N + 31) / 32, 256, 0, stream>>>(x, W1, nullptr, bufA, N);
    propagate_kernel<8, true><<<(N + 31) / 32, 256, 0, stream>>>(bufA, bufB, row_ptr, col, ew, dinv, b1, N);

    // L2: propagate-first (8), then transform 8->16 (+b2, relu)
    propagate_kernel<8, false><<<(N + 31) / 32, 256, 0, stream>>>(bufB, bufA, row_ptr, col, ew, dinv, nullptr, N);
    transform_kernel<8, 16, 1, true><<<(N + 15) / 16, 256, 0, stream>>>(bufA, W2, b2, bufB, N);

    // L3: propagate (16), transform 16->64
    propagate_kernel<16, false><<<(N + 15) / 16, 256, 0, stream>>>(bufB, bufA, row_ptr, col, ew, dinv, nullptr, N);
    transform_kernel<16, 64, 2, true><<<(N + 7) / 8, 256, 0, stream>>>(bufA, W3, b3, bufB, N);

    // L4: propagate (64), transform 64->256
    propagate_kernel<64, false><<<(N + 3) / 4, 256, 0, stream>>>(bufB, bufA, row_ptr, col, ew, dinv, nullptr, N);
    transform_kernel<64, 256, 8, true><<<(N + 7) / 8, 256, 0, stream>>>(bufA, W4, b4, bufB, N);

    // L5: propagate (256), then GEMM (256->512) + bias + relu + fused mean-pool
    propagate_kernel<256, false><<<N, 256, 0, stream>>>(bufB, bufA, row_ptr, col, ew, dinv, nullptr, N);
    dim3 g5((N + 127) / 128, 8);
    gemm5_pool<<<g5, 256, 0, stream>>>(bufA, W5, b5, batch, out, N);
    divide_kernel<<<(NGRAPH * 512 + 255) / 256, 256, 0, stream>>>(out, cntB, NGRAPH * 512);
}

// Round 4
// 1035.134 us; speedup vs baseline: 2.2900x; 2.2900x over previous
//
#include <hip/hip_runtime.h>
#include <hip/hip_bf16.h>

#define NNODES 50000
#define NEDGES 400000
#define NGRAPH 50

// ---------------- CSR build ----------------

__global__ void count_kernel(const int* __restrict__ dst, int* __restrict__ cnt, int E) {
    int e = blockIdx.x * 256 + threadIdx.x;
    if (e < E) atomicAdd(&cnt[dst[e]], 1);
}

__global__ void dinv_kernel(const int* __restrict__ cnt, float* __restrict__ dinv, int N) {
    int i = blockIdx.x * 256 + threadIdx.x;
    if (i < N) dinv[i] = rsqrtf((float)cnt[i] + 1.0f);
}

// single-block exclusive scan: row_ptr[0]=0, row_ptr[i+1]=sum cnt[0..i]
__global__ void scan_kernel(const int* __restrict__ cnt, int* __restrict__ row_ptr, int N) {
    __shared__ int sm[1024];
    __shared__ int carry;
    int t = threadIdx.x;
    if (t == 0) { carry = 0; row_ptr[0] = 0; }
    __syncthreads();
    for (int base = 0; base < N; base += 1024) {
        int i = base + t;
        int v = (i < N) ? cnt[i] : 0;
        sm[t] = v;
        __syncthreads();
        for (int off = 1; off < 1024; off <<= 1) {
            int x = (t >= off) ? sm[t - off] : 0;
            __syncthreads();
            sm[t] += x;
            __syncthreads();
        }
        int total = sm[1023];
        if (i < N) row_ptr[i + 1] = carry + sm[t];
        __syncthreads();
        if (t == 0) carry += total;
        __syncthreads();
    }
}

__global__ void fill_kernel(const int* __restrict__ src, const int* __restrict__ dst,
                            const int* __restrict__ row_ptr, int* __restrict__ fill,
                            const float* __restrict__ dinv,
                            int* __restrict__ col, float* __restrict__ ew, int E) {
    int e = blockIdx.x * 256 + threadIdx.x;
    if (e < E) {
        int s = src[e], d = dst[e];
        int pos = row_ptr[d] + atomicAdd(&fill[d], 1);
        col[pos] = s;
        ew[pos] = dinv[s] * dinv[d];
    }
}

__global__ void countb_kernel(const int* __restrict__ batch, int* __restrict__ cntB, int N) {
    int i = blockIdx.x * 256 + threadIdx.x;
    if (i < N) atomicAdd(&cntB[batch[i]], 1);
}

// ---------------- persistent dense transform: Y = [relu](X @ W [+ b]) ----------------
// W staged in LDS ONCE per block; grid-stride over row tiles of RPT rows.
// RT = RPT*COUT/256 rows per thread; thread handles column j = t % COUT.

template <int CIN, int COUT, int RPT, bool PR>
__global__ __launch_bounds__(256) void transform_persist(const float* __restrict__ X,
                                                         const float* __restrict__ W,
                                                         const float* __restrict__ bias,
                                                         float* __restrict__ Y, int N) {
    constexpr int RT = RPT * COUT / 256;
    __shared__ float Ws[CIN * COUT];
    __shared__ float ps[RPT * CIN];
    int t = threadIdx.x;
    for (int i = t; i < CIN * COUT; i += 256) Ws[i] = W[i];

    int j = t % COUT;
    int lb = (t / COUT) * RT;
    float bv = 0.f;
    if constexpr (PR) bv = bias[j];

    int ntiles = (N + RPT - 1) / RPT;
    for (int tile = blockIdx.x; tile < ntiles; tile += gridDim.x) {
        int row0 = tile * RPT;
        __syncthreads();   // prev iter done with ps; first iter: Ws fill visible after next sync
        for (int i = t; i < RPT * CIN; i += 256) {
            int r = row0 + i / CIN;
            ps[i] = (r < N) ? X[r * CIN + (i % CIN)] : 0.f;
        }
        __syncthreads();

        float acc[RT];
        #pragma unroll
        for (int r = 0; r < RT; ++r) acc[r] = bv;
        #pragma unroll
        for (int k = 0; k < CIN; ++k) {
            float w = Ws[k * COUT + j];
            #pragma unroll
            for (int r = 0; r < RT; ++r) acc[r] += ps[(lb + r) * CIN + k] * w;
        }
        #pragma unroll
        for (int r = 0; r < RT; ++r) {
            int row = row0 + lb + r;
            if (row < N) {
                float v = acc[r];
                if constexpr (PR) v = fmaxf(v, 0.f);
                Y[row * COUT + j] = v;
            }
        }
    }
}

// ---------------- propagation: xout = Ahat xin  [+bias, relu] ----------------
// pull-style over CSR(dst); C channels, 256/C nodes per block.

template <int C, bool PR>
__global__ void propagate_kernel(const float* __restrict__ xin, float* __restrict__ xout,
                                 const int* __restrict__ row_ptr, const int* __restrict__ col,
                                 const float* __restrict__ ew, const float* __restrict__ dinv,
                                 const float* __restrict__ bias, int N) {
    constexpr int NPB = 256 / C;
    int t = threadIdx.x;
    int node = blockIdx.x * NPB + t / C;
    int ch = t % C;
    if (node >= N) return;
    float di = dinv[node];
    float acc = xin[node * C + ch] * di * di;   // self-loop term
    int e0 = row_ptr[node], e1 = row_ptr[node + 1];
    for (int e = e0; e < e1; ++e) {
        int s = col[e];
        float w = ew[e];
        acc += xin[s * C + ch] * w;
    }
    if constexpr (PR) acc = fmaxf(acc + bias[ch], 0.f);
    xout[node * C + ch] = acc;
}

// ---------------- layer 5 GEMM (N,256)x(256,512) + bias + relu + mean-pool ----------------
// 128x64 tile, K-step 16, 256 threads, 8x4 microtile. Pool fused via LDS reduction
// (batch is sorted; per-block uniform fast path, atomic fallback at graph boundaries).

__global__ __launch_bounds__(256) void gemm5_pool(const float* __restrict__ A, const float* __restrict__ W,
                                                  const float* __restrict__ bias, const int* __restrict__ batch,
                                                  float* __restrict__ out, int N) {
    __shared__ float As[16][128];
    __shared__ float Bs[16][64];
    __shared__ float red[16][64];
    int t = threadIdx.x;
    int tx = t % 16, ty = t / 16;
    int row0 = blockIdx.x * 128;
    int col0 = blockIdx.y * 64;
    float acc[8][4];
    #pragma unroll
    for (int i = 0; i < 8; ++i)
        #pragma unroll
        for (int j = 0; j < 4; ++j) acc[i][j] = 0.f;

    for (int kc = 0; kc < 256; kc += 16) {
        #pragma unroll
        for (int it = 0; it < 2; ++it) {
            int idx = t + it * 256;        // 0..511
            int row = idx / 4;             // 0..127
            int kq = (idx % 4) * 4;
            int gr = row0 + row; if (gr > N - 1) gr = N - 1;
            const float4 v = *reinterpret_cast<const float4*>(&A[gr * 256 + kc + kq]);
            As[kq + 0][row] = v.x; As[kq + 1][row] = v.y;
            As[kq + 2][row] = v.z; As[kq + 3][row] = v.w;
        }
        {
            int kk = t / 16;
            int c4 = (t % 16) * 4;
            const float4 v = *reinterpret_cast<const float4*>(&W[(kc + kk) * 512 + col0 + c4]);
            *reinterpret_cast<float4*>(&Bs[kk][c4]) = v;
        }
        __syncthreads();
        #pragma unroll
        for (int kk = 0; kk < 16; ++kk) {
            float aL[8], bL[4];
            #pragma unroll
            for (int i = 0; i < 8; ++i) aL[i] = As[kk][ty + 16 * i];
            #pragma unroll
            for (int j = 0; j < 4; ++j) bL[j] = Bs[kk][tx + 16 * j];
            #pragma unroll
            for (int i = 0; i < 8; ++i)
                #pragma unroll
                for (int j = 0; j < 4; ++j) acc[i][j] += aL[i] * bL[j];
        }
        __syncthreads();
    }

    #pragma unroll
    for (int j = 0; j < 4; ++j) {
        float bv = bias[col0 + tx + 16 * j];
        #pragma unroll
        for (int i = 0; i < 8; ++i) acc[i][j] = fmaxf(acc[i][j] + bv, 0.f);
    }

    int rlast = row0 + 127; if (rlast > N - 1) rlast = N - 1;
    int b0 = batch[row0];
    int b1 = batch[rlast];
    if (b0 == b1) {
        #pragma unroll
        for (int j = 0; j < 4; ++j) {
            float p = 0.f;
            #pragma unroll
            for (int i = 0; i < 8; ++i) {
                int r = row0 + ty + 16 * i;
                if (r < N) p += acc[i][j];
            }
            red[ty][tx + 16 * j] = p;
        }
        __syncthreads();
        if (t < 64) {
            float s = 0.f;
            #pragma unroll
            for (int yy = 0; yy < 16; ++yy) s += red[yy][t];
            atomicAdd(&out[b0 * 512 + col0 + t], s);
        }
    } else {
        #pragma unroll
        for (int i = 0; i < 8; ++i) {
            int r = row0 + ty + 16 * i;
            if (r < N) {
                int bb = batch[r];
                #pragma unroll
                for (int j = 0; j < 4; ++j)
                    atomicAdd(&out[bb * 512 + col0 + tx + 16 * j], acc[i][j]);
            }
        }
    }
}

__global__ void divide_kernel(float* __restrict__ out, const int* __restrict__ cntB, int total) {
    int i = blockIdx.x * 256 + threadIdx.x;
    if (i < total) out[i] /= fmaxf((float)cntB[i >> 9], 1.f);
}

// ---------------- launch ----------------

extern "C" void kernel_launch(void* const* d_in, const int* in_sizes, int n_in,
                              void* d_out, int out_size, void* d_ws, size_t ws_size,
                              hipStream_t stream) {
    const float* x   = (const float*)d_in[0];
    const int* ei    = (const int*)d_in[1];
    const int* batch = (const int*)d_in[2];
    const float* W1 = (const float*)d_in[3];  const float* b1 = (const float*)d_in[4];
    const float* W2 = (const float*)d_in[5];  const float* b2 = (const float*)d_in[6];
    const float* W3 = (const float*)d_in[7];  const float* b3 = (const float*)d_in[8];
    const float* W4 = (const float*)d_in[9];  const float* b4 = (const float*)d_in[10];
    const float* W5 = (const float*)d_in[11]; const float* b5 = (const float*)d_in[12];
    float* out = (float*)d_out;

    const int N = NNODES, E = NEDGES;
    const int* src = ei;
    const int* dst = ei + E;

    char* ws = (char*)d_ws;
    size_t off = 0;
    auto alloc = [&](size_t bytes) {
        void* p = ws + off;
        off += (bytes + 255) & ~size_t(255);
        return p;
    };
    float* bufA   = (float*)alloc(sizeof(float) * size_t(N) * 256);
    float* bufB   = (float*)alloc(sizeof(float) * size_t(N) * 256);
    int* cnt      = (int*)alloc(sizeof(int) * N);
    int* fill     = (int*)alloc(sizeof(int) * N);
    int* row_ptr  = (int*)alloc(sizeof(int) * (N + 1));
    int* col      = (int*)alloc(sizeof(int) * E);
    float* ew     = (float*)alloc(sizeof(float) * E);
    float* dinv   = (float*)alloc(sizeof(float) * N);
    int* cntB     = (int*)alloc(sizeof(int) * NGRAPH);

    hipMemsetAsync(cnt, 0, sizeof(int) * N, stream);
    hipMemsetAsync(fill, 0, sizeof(int) * N, stream);
    hipMemsetAsync(cntB, 0, sizeof(int) * NGRAPH, stream);
    hipMemsetAsync(out, 0, sizeof(float) * out_size, stream);

    count_kernel<<<(E + 255) / 256, 256, 0, stream>>>(dst, cnt, E);
    dinv_kernel<<<(N + 255) / 256, 256, 0, stream>>>(cnt, dinv, N);
    scan_kernel<<<1, 1024, 0, stream>>>(cnt, row_ptr, N);
    fill_kernel<<<(E + 255) / 256, 256, 0, stream>>>(src, dst, row_ptr, fill, dinv, col, ew, E);
    countb_kernel<<<(N + 255) / 256, 256, 0, stream>>>(batch, cntB, N);

    // L1: transform-first (32 -> 8), then propagate (+b1, relu). ntiles = ceil(N/32) = 1563
    transform_persist<32, 8, 32, false><<<1024, 256, 0, stream>>>(x, W1, nullptr, bufA, N);
    propagate_kernel<8, true><<<(N + 31) / 32, 256, 0, stream>>>(bufA, bufB, row_ptr, col, ew, dinv, b1, N);

    // L2: propagate-first (8), then transform 8->16. ntiles = 1563
    propagate_kernel<8, false><<<(N + 31) / 32, 256, 0, stream>>>(bufB, bufA, row_ptr, col, ew, dinv, nullptr, N);
    transform_persist<8, 16, 32, true><<<1024, 256, 0, stream>>>(bufA, W2, b2, bufB, N);

    // L3: propagate (16), transform 16->64. ntiles = ceil(N/16) = 3125
    propagate_kernel<16, false><<<(N + 15) / 16, 256, 0, stream>>>(bufB, bufA, row_ptr, col, ew, dinv, nullptr, N);
    transform_persist<16, 64, 16, true><<<1024, 256, 0, stream>>>(bufA, W3, b3, bufB, N);

    // L4: propagate (64), transform 64->256. 66KB LDS -> 2 blocks/CU -> grid 512, ~12 tiles/block
    propagate_kernel<64, false><<<(N + 3) / 4, 256, 0, stream>>>(bufB, bufA, row_ptr, col, ew, dinv, nullptr, N);
    transform_persist<64, 256, 8, true><<<512, 256, 0, stream>>>(bufA, W4, b4, bufB, N);

    // L5: propagate (256), then GEMM (256->512) + bias + relu + fused mean-pool
    propagate_kernel<256, false><<<N, 256, 0, stream>>>(bufB, bufA, row_ptr, col, ew, dinv, nullptr, N);
    dim3 g5((N + 127) / 128, 8);
    gemm5_pool<<<g5, 256, 0, stream>>>(bufA, W5, b5, batch, out, N);
    divide_kernel<<<(NGRAPH * 512 + 255) / 256, 256, 0, stream>>>(out, cntB, NGRAPH * 512);
}

// Round 6
// 839.089 us; speedup vs baseline: 2.8250x; 1.2336x over previous
//
#include <hip/hip_runtime.h>
#include <hip/hip_bf16.h>

#define NNODES 50000
#define NEDGES 400000
#define NGRAPH 50

typedef __bf16 bf16_t;
typedef __bf16 bf16x4_t __attribute__((ext_vector_type(4)));
typedef __bf16 bf16x8_t __attribute__((ext_vector_type(8)));
typedef float f32x4_t __attribute__((ext_vector_type(4)));

// ---------------- CSR build ----------------

__global__ void count_kernel(const int* __restrict__ dst, int* __restrict__ cnt, int E) {
    int e = blockIdx.x * 256 + threadIdx.x;
    if (e < E) atomicAdd(&cnt[dst[e]], 1);
}

__global__ void dinv_kernel(const int* __restrict__ cnt, float* __restrict__ dinv, int N) {
    int i = blockIdx.x * 256 + threadIdx.x;
    if (i < N) dinv[i] = rsqrtf((float)cnt[i] + 1.0f);
}

// hierarchical scan: pass1 per-block inclusive scan + block sums
__global__ void scan_part(const int* __restrict__ cnt, int* __restrict__ bsum,
                          int* __restrict__ pre, int N) {
    __shared__ int sm[256];
    int t = threadIdx.x;
    int i = blockIdx.x * 256 + t;
    sm[t] = (i < N) ? cnt[i] : 0;
    __syncthreads();
    for (int off = 1; off < 256; off <<= 1) {
        int x = (t >= off) ? sm[t - off] : 0;
        __syncthreads();
        sm[t] += x;
        __syncthreads();
    }
    if (i < N) pre[i] = sm[t];
    if (t == 255) bsum[blockIdx.x] = sm[255];
}

// pass2: single block scans <=256 block sums (inclusive)
__global__ void scan_bsum(int* __restrict__ bsum, int nb) {
    __shared__ int sm[256];
    int t = threadIdx.x;
    sm[t] = (t < nb) ? bsum[t] : 0;
    __syncthreads();
    for (int off = 1; off < 256; off <<= 1) {
        int x = (t >= off) ? sm[t - off] : 0;
        __syncthreads();
        sm[t] += x;
        __syncthreads();
    }
    if (t < nb) bsum[t] = sm[t];
}

// pass3: row_ptr[i+1] = pre[i] + offset(block)
__global__ void scan_final(const int* __restrict__ pre, const int* __restrict__ bsum,
                           int* __restrict__ row_ptr, int N) {
    int i = blockIdx.x * 256 + threadIdx.x;
    if (i == 0) row_ptr[0] = 0;
    if (i < N) {
        int off = (blockIdx.x > 0) ? bsum[blockIdx.x - 1] : 0;
        row_ptr[i + 1] = off + pre[i];
    }
}

__global__ void fill_kernel(const int* __restrict__ src, const int* __restrict__ dst,
                            const int* __restrict__ row_ptr, int* __restrict__ fill,
                            const float* __restrict__ dinv,
                            int* __restrict__ col, float* __restrict__ ew, int E) {
    int e = blockIdx.x * 256 + threadIdx.x;
    if (e < E) {
        int s = src[e], d = dst[e];
        int pos = row_ptr[d] + atomicAdd(&fill[d], 1);
        col[pos] = s;
        ew[pos] = dinv[s] * dinv[d];
    }
}

__global__ void countb_kernel(const int* __restrict__ batch, int* __restrict__ cntB, int N) {
    int i = blockIdx.x * 256 + threadIdx.x;
    if (i < N) atomicAdd(&cntB[batch[i]], 1);
}

// W5 prep: split into hi/lo bf16, transposed to [col][k] (B^T layout for MFMA frags)
__global__ void prep_w5(const float* __restrict__ W, bf16_t* __restrict__ hi,
                        bf16_t* __restrict__ lo) {
    int i = blockIdx.x * 256 + threadIdx.x;   // over 256*512
    if (i < 256 * 512) {
        int k = i / 512, c = i % 512;
        float v = W[i];
        bf16_t h = (bf16_t)v;
        float r = v - (float)h;
        hi[c * 256 + k] = h;
        lo[c * 256 + k] = (bf16_t)r;
    }
}

// ---------------- persistent dense transform: Y = [relu](X @ W [+ b]) ----------------

template <int CIN, int COUT, int RPT, bool PR, typename OutT = float>
__global__ __launch_bounds__(256) void transform_persist(const float* __restrict__ X,
                                                         const float* __restrict__ W,
                                                         const float* __restrict__ bias,
                                                         OutT* __restrict__ Y, int N) {
    constexpr int RT = RPT * COUT / 256;
    __shared__ float Ws[CIN * COUT];
    __shared__ float ps[RPT * CIN];
    int t = threadIdx.x;
    for (int i = t; i < CIN * COUT; i += 256) Ws[i] = W[i];

    int j = t % COUT;
    int lb = (t / COUT) * RT;
    float bv = 0.f;
    if constexpr (PR) bv = bias[j];

    int ntiles = (N + RPT - 1) / RPT;
    for (int tile = blockIdx.x; tile < ntiles; tile += gridDim.x) {
        int row0 = tile * RPT;
        __syncthreads();
        for (int i = t; i < RPT * CIN; i += 256) {
            int r = row0 + i / CIN;
            ps[i] = (r < N) ? X[r * CIN + (i % CIN)] : 0.f;
        }
        __syncthreads();

        float acc[RT];
        #pragma unroll
        for (int r = 0; r < RT; ++r) acc[r] = bv;
        #pragma unroll
        for (int k = 0; k < CIN; ++k) {
            float w = Ws[k * COUT + j];
            #pragma unroll
            for (int r = 0; r < RT; ++r) acc[r] += ps[(lb + r) * CIN + k] * w;
        }
        #pragma unroll
        for (int r = 0; r < RT; ++r) {
            int row = row0 + lb + r;
            if (row < N) {
                float v = acc[r];
                if constexpr (PR) v = fmaxf(v, 0.f);
                Y[row * COUT + j] = (OutT)v;
            }
        }
    }
}

// ---------------- propagation fp32 (layers 1-4): xout = Ahat xin [+bias, relu] ----------------

template <int C, bool PR>
__global__ void propagate_kernel(const float* __restrict__ xin, float* __restrict__ xout,
                                 const int* __restrict__ row_ptr, const int* __restrict__ col,
                                 const float* __restrict__ ew, const float* __restrict__ dinv,
                                 const float* __restrict__ bias, int N) {
    constexpr int NPB = 256 / C;
    int t = threadIdx.x;
    int node = blockIdx.x * NPB + t / C;
    int ch = t % C;
    if (node >= N) return;
    float di = dinv[node];
    float acc = xin[node * C + ch] * di * di;
    int e0 = row_ptr[node], e1 = row_ptr[node + 1];
    for (int e = e0; e < e1; ++e) {
        acc += xin[col[e] * C + ch] * ew[e];
    }
    if constexpr (PR) acc = fmaxf(acc + bias[ch], 0.f);
    xout[node * C + ch] = acc;
}

// ---------------- propagation bf16, C=256: 1 node per wave, 4 ch/lane ----------------

__global__ __launch_bounds__(256) void propagate256_bf16(
    const bf16_t* __restrict__ xin, bf16_t* __restrict__ xout,
    const int* __restrict__ row_ptr, const int* __restrict__ col,
    const float* __restrict__ ew, const float* __restrict__ dinv, int N)
{
    int t = threadIdx.x;
    int node = blockIdx.x * 4 + (t >> 6);
    if (node >= N) return;
    int lane = t & 63;
    size_t base = (size_t)node * 256 + lane * 4;
    float di = dinv[node];
    float sn = di * di;
    bf16x4_t sv = *reinterpret_cast<const bf16x4_t*>(&xin[base]);
    float a0 = (float)sv[0] * sn, a1 = (float)sv[1] * sn;
    float a2 = (float)sv[2] * sn, a3 = (float)sv[3] * sn;
    int e0 = row_ptr[node], e1 = row_ptr[node + 1];
    for (int e = e0; e < e1; ++e) {
        int s = col[e];
        float w = ew[e];
        bf16x4_t v = *reinterpret_cast<const bf16x4_t*>(&xin[(size_t)s * 256 + lane * 4]);
        a0 += w * (float)v[0]; a1 += w * (float)v[1];
        a2 += w * (float)v[2]; a3 += w * (float)v[3];
    }
    bf16x4_t o;
    o[0] = (bf16_t)a0; o[1] = (bf16_t)a1; o[2] = (bf16_t)a2; o[3] = (bf16_t)a3;
    *reinterpret_cast<bf16x4_t*>(&xout[base]) = o;
}

// ---------------- L5: MFMA GEMM (N,256)x(256,512) bf16 + bias + relu + fused mean-pool ----
// A bf16 [N][256]; W split hi/lo bf16 in B^T layout [512][256]. 128x64 tile/block, 4 waves,
// wave = 32 rows x 64 cols = 2x4 frags of 16x16x32. No LDS in main loop (L2-broadcast W).

__global__ __launch_bounds__(256) void gemm5_pool_mfma(
    const bf16_t* __restrict__ A, const bf16_t* __restrict__ Wth,
    const bf16_t* __restrict__ Wtl, const float* __restrict__ bias,
    const int* __restrict__ batch, float* __restrict__ out, int N)
{
    __shared__ float red[64];
    int t = threadIdx.x;
    int wave = t >> 6, lane = t & 63;
    int lr = lane & 15, kg = lane >> 4;
    int brow = blockIdx.x * 128;
    int row0 = brow + wave * 32;
    int col0 = blockIdx.y * 64;

    f32x4_t acc[2][4];
    #pragma unroll
    for (int i = 0; i < 2; ++i)
        #pragma unroll
        for (int j = 0; j < 4; ++j) {
            f32x4_t z = {0.f, 0.f, 0.f, 0.f};
            acc[i][j] = z;
        }

    int ra = row0 + lr;      if (ra > N - 1) ra = N - 1;
    int rb = row0 + 16 + lr; if (rb > N - 1) rb = N - 1;
    const bf16_t* pa = A + (size_t)ra * 256 + kg * 8;
    const bf16_t* pb = A + (size_t)rb * 256 + kg * 8;

    #pragma unroll
    for (int kc = 0; kc < 256; kc += 32) {
        bf16x8_t a0 = *reinterpret_cast<const bf16x8_t*>(pa + kc);
        bf16x8_t a1 = *reinterpret_cast<const bf16x8_t*>(pb + kc);
        #pragma unroll
        for (int cf = 0; cf < 4; ++cf) {
            size_t bo = (size_t)(col0 + cf * 16 + lr) * 256 + kc + kg * 8;
            bf16x8_t bh = *reinterpret_cast<const bf16x8_t*>(&Wth[bo]);
            bf16x8_t bl = *reinterpret_cast<const bf16x8_t*>(&Wtl[bo]);
            acc[0][cf] = __builtin_amdgcn_mfma_f32_16x16x32_bf16(a0, bh, acc[0][cf], 0, 0, 0);
            acc[0][cf] = __builtin_amdgcn_mfma_f32_16x16x32_bf16(a0, bl, acc[0][cf], 0, 0, 0);
            acc[1][cf] = __builtin_amdgcn_mfma_f32_16x16x32_bf16(a1, bh, acc[1][cf], 0, 0, 0);
            acc[1][cf] = __builtin_amdgcn_mfma_f32_16x16x32_bf16(a1, bl, acc[1][cf], 0, 0, 0);
        }
    }

    // bias + relu. C/D layout: col = col0+cf*16+lr, row = row0+rf*16+kg*4+g
    float bv[4];
    #pragma unroll
    for (int cf = 0; cf < 4; ++cf) bv[cf] = bias[col0 + cf * 16 + lr];
    float v[2][4][4];
    #pragma unroll
    for (int rf = 0; rf < 2; ++rf)
        #pragma unroll
        for (int cf = 0; cf < 4; ++cf)
            #pragma unroll
            for (int g = 0; g < 4; ++g)
                v[rf][cf][g] = fmaxf(acc[rf][cf][g] + bv[cf], 0.f);

    int rlast = brow + 127; if (rlast > N - 1) rlast = N - 1;
    int b0 = batch[brow];
    if (b0 == batch[rlast]) {          // block-uniform branch
        if (t < 64) red[t] = 0.f;
        __syncthreads();
        #pragma unroll
        for (int cf = 0; cf < 4; ++cf) {
            float s = 0.f;
            #pragma unroll
            for (int rf = 0; rf < 2; ++rf)
                #pragma unroll
                for (int g = 0; g < 4; ++g) {
                    int r = row0 + rf * 16 + kg * 4 + g;
                    s += (r < N) ? v[rf][cf][g] : 0.f;
                }
            s += __shfl_xor(s, 16, 64);
            s += __shfl_xor(s, 32, 64);
            if (lane < 16) atomicAdd(&red[cf * 16 + lr], s);
        }
        __syncthreads();
        if (t < 64) atomicAdd(&out[(size_t)b0 * 512 + col0 + t], red[t]);
    } else {
        #pragma unroll
        for (int rf = 0; rf < 2; ++rf)
            #pragma unroll
            for (int g = 0; g < 4; ++g) {
                int r = row0 + rf * 16 + kg * 4 + g;
                if (r < N) {
                    int bb = batch[r];
                    #pragma unroll
                    for (int cf = 0; cf < 4; ++cf)
                        atomicAdd(&out[(size_t)bb * 512 + col0 + cf * 16 + lr], v[rf][cf][g]);
                }
            }
    }
}

__global__ void divide_kernel(float* __restrict__ out, const int* __restrict__ cntB, int total) {
    int i = blockIdx.x * 256 + threadIdx.x;
    if (i < total) out[i] /= fmaxf((float)cntB[i >> 9], 1.f);
}

// ---------------- launch ----------------

extern "C" void kernel_launch(void* const* d_in, const int* in_sizes, int n_in,
                              void* d_out, int out_size, void* d_ws, size_t ws_size,
                              hipStream_t stream) {
    const float* x   = (const float*)d_in[0];
    const int* ei    = (const int*)d_in[1];
    const int* batch = (const int*)d_in[2];
    const float* W1 = (const float*)d_in[3];  const float* b1 = (const float*)d_in[4];
    const float* W2 = (const float*)d_in[5];  const float* b2 = (const float*)d_in[6];
    const float* W3 = (const float*)d_in[7];  const float* b3 = (const float*)d_in[8];
    const float* W4 = (const float*)d_in[9];  const float* b4 = (const float*)d_in[10];
    const float* W5 = (const float*)d_in[11]; const float* b5 = (const float*)d_in[12];
    float* out = (float*)d_out;

    const int N = NNODES, E = NEDGES;
    const int* src = ei;
    const int* dst = ei + E;

    char* ws = (char*)d_ws;
    size_t off = 0;
    auto alloc = [&](size_t bytes) {
        void* p = ws + off;
        off += (bytes + 255) & ~size_t(255);
        return p;
    };
    float* bufA   = (float*)alloc(sizeof(float) * size_t(N) * 256);
    float* bufB   = (float*)alloc(sizeof(float) * size_t(N) * 256);
    int* cnt      = (int*)alloc(sizeof(int) * N);
    int* fill     = (int*)alloc(sizeof(int) * N);
    int* row_ptr  = (int*)alloc(sizeof(int) * (N + 1));
    int* col      = (int*)alloc(sizeof(int) * E);
    float* ew     = (float*)alloc(sizeof(float) * E);
    float* dinv   = (float*)alloc(sizeof(float) * N);
    int* cntB     = (int*)alloc(sizeof(int) * NGRAPH);
    int* pre      = (int*)alloc(sizeof(int) * N);
    int* bsum     = (int*)alloc(sizeof(int) * 256);
    bf16_t* wt_hi = (bf16_t*)alloc(sizeof(bf16_t) * 512 * 256);
    bf16_t* wt_lo = (bf16_t*)alloc(sizeof(bf16_t) * 512 * 256);

    hipMemsetAsync(cnt, 0, sizeof(int) * N, stream);
    hipMemsetAsync(fill, 0, sizeof(int) * N, stream);
    hipMemsetAsync(cntB, 0, sizeof(int) * NGRAPH, stream);
    hipMemsetAsync(out, 0, sizeof(float) * out_size, stream);

    count_kernel<<<(E + 255) / 256, 256, 0, stream>>>(dst, cnt, E);
    dinv_kernel<<<(N + 255) / 256, 256, 0, stream>>>(cnt, dinv, N);
    int nb = (N + 255) / 256;   // 196
    scan_part<<<nb, 256, 0, stream>>>(cnt, bsum, pre, N);
    scan_bsum<<<1, 256, 0, stream>>>(bsum, nb);
    scan_final<<<nb, 256, 0, stream>>>(pre, bsum, row_ptr, N);
    fill_kernel<<<(E + 255) / 256, 256, 0, stream>>>(src, dst, row_ptr, fill, dinv, col, ew, E);
    countb_kernel<<<(N + 255) / 256, 256, 0, stream>>>(batch, cntB, N);
    prep_w5<<<(256 * 512 + 255) / 256, 256, 0, stream>>>(W5, wt_hi, wt_lo);

    // L1: transform-first (32 -> 8), then propagate (+b1, relu)
    transform_persist<32, 8, 32, false><<<1024, 256, 0, stream>>>(x, W1, nullptr, bufA, N);
    propagate_kernel<8, true><<<(N + 31) / 32, 256, 0, stream>>>(bufA, bufB, row_ptr, col, ew, dinv, b1, N);

    // L2: propagate-first (8), then transform 8->16
    propagate_kernel<8, false><<<(N + 31) / 32, 256, 0, stream>>>(bufB, bufA, row_ptr, col, ew, dinv, nullptr, N);
    transform_persist<8, 16, 32, true><<<1024, 256, 0, stream>>>(bufA, W2, b2, bufB, N);

    // L3: propagate (16), transform 16->64
    propagate_kernel<16, false><<<(N + 15) / 16, 256, 0, stream>>>(bufB, bufA, row_ptr, col, ew, dinv, nullptr, N);
    transform_persist<16, 64, 16, true><<<1024, 256, 0, stream>>>(bufA, W3, b3, bufB, N);

    // L4: propagate (64), transform 64->256 with bf16 output (into bufB region)
    propagate_kernel<64, false><<<(N + 3) / 4, 256, 0, stream>>>(bufB, bufA, row_ptr, col, ew, dinv, nullptr, N);
    bf16_t* h4b = (bf16_t*)bufB;
    transform_persist<64, 256, 8, true, bf16_t><<<512, 256, 0, stream>>>(bufA, W4, b4, h4b, N);

    // L5: propagate bf16 (256), then MFMA GEMM + bias + relu + fused mean-pool
    bf16_t* h5in = (bf16_t*)bufA;
    propagate256_bf16<<<(N + 3) / 4, 256, 0, stream>>>(h4b, h5in, row_ptr, col, ew, dinv, N);
    dim3 g5((N + 127) / 128, 8);
    gemm5_pool_mfma<<<g5, 256, 0, stream>>>(h5in, wt_hi, wt_lo, b5, batch, out, N);
    divide_kernel<<<(NGRAPH * 512 + 255) / 256, 256, 0, stream>>>(out, cntB, NGRAPH * 512);
}

// Round 7
// 598.210 us; speedup vs baseline: 3.9626x; 1.4027x over previous
//
#include <hip/hip_runtime.h>
#include <hip/hip_bf16.h>

#define NNODES 50000
#define NEDGES 400000
#define NGRAPH 50

typedef __bf16 bf16_t;
typedef __bf16 bf16x4_t __attribute__((ext_vector_type(4)));
typedef __bf16 bf16x8_t __attribute__((ext_vector_type(8)));
typedef float f32x4_t __attribute__((ext_vector_type(4)));

// ---------------- CSR build ----------------

__global__ void count_kernel(const int* __restrict__ dst, int* __restrict__ cnt, int E) {
    int e = blockIdx.x * 256 + threadIdx.x;
    if (e < E) atomicAdd(&cnt[dst[e]], 1);
}

__global__ void dinv_kernel(const int* __restrict__ cnt, float* __restrict__ dinv, int N) {
    int i = blockIdx.x * 256 + threadIdx.x;
    if (i < N) dinv[i] = rsqrtf((float)cnt[i] + 1.0f);
}

// hierarchical scan: pass1 per-block inclusive scan + block sums
__global__ void scan_part(const int* __restrict__ cnt, int* __restrict__ bsum,
                          int* __restrict__ pre, int N) {
    __shared__ int sm[256];
    int t = threadIdx.x;
    int i = blockIdx.x * 256 + t;
    sm[t] = (i < N) ? cnt[i] : 0;
    __syncthreads();
    for (int off = 1; off < 256; off <<= 1) {
        int x = (t >= off) ? sm[t - off] : 0;
        __syncthreads();
        sm[t] += x;
        __syncthreads();
    }
    if (i < N) pre[i] = sm[t];
    if (t == 255) bsum[blockIdx.x] = sm[255];
}

// pass2: single block scans <=256 block sums (inclusive)
__global__ void scan_bsum(int* __restrict__ bsum, int nb) {
    __shared__ int sm[256];
    int t = threadIdx.x;
    sm[t] = (t < nb) ? bsum[t] : 0;
    __syncthreads();
    for (int off = 1; off < 256; off <<= 1) {
        int x = (t >= off) ? sm[t - off] : 0;
        __syncthreads();
        sm[t] += x;
        __syncthreads();
    }
    if (t < nb) bsum[t] = sm[t];
}

// pass3: row_ptr[i+1] = pre[i] + offset(block)
__global__ void scan_final(const int* __restrict__ pre, const int* __restrict__ bsum,
                           int* __restrict__ row_ptr, int N) {
    int i = blockIdx.x * 256 + threadIdx.x;
    if (i == 0) row_ptr[0] = 0;
    if (i < N) {
        int off = (blockIdx.x > 0) ? bsum[blockIdx.x - 1] : 0;
        row_ptr[i + 1] = off + pre[i];
    }
}

__global__ void fill_kernel(const int* __restrict__ src, const int* __restrict__ dst,
                            const int* __restrict__ row_ptr, int* __restrict__ fill,
                            const float* __restrict__ dinv,
                            int* __restrict__ col, float* __restrict__ ew, int E) {
    int e = blockIdx.x * 256 + threadIdx.x;
    if (e < E) {
        int s = src[e], d = dst[e];
        int pos = row_ptr[d] + atomicAdd(&fill[d], 1);
        col[pos] = s;
        ew[pos] = dinv[s] * dinv[d];
    }
}

// batch is SORTED: find graph start offsets with one coalesced pass, zero atomics.
// start[g] = first node of graph g; start[NGRAPH] = N. Empty graphs get start[g]=start[g+1].
__global__ void graph_starts(const int* __restrict__ batch, int* __restrict__ start, int N) {
    int i = blockIdx.x * 256 + threadIdx.x;
    if (i >= N) return;
    int b = batch[i];
    if (i == 0) {
        for (int g = 0; g <= b; ++g) start[g] = 0;
    } else {
        int p = batch[i - 1];
        for (int g = p + 1; g <= b; ++g) start[g] = i;
    }
    if (i == N - 1) {
        for (int g = b + 1; g <= NGRAPH; ++g) start[g] = N;
    }
}

// W5 prep: split into hi/lo bf16, transposed to [col][k] (B^T layout for MFMA frags)
__global__ void prep_w5(const float* __restrict__ W, bf16_t* __restrict__ hi,
                        bf16_t* __restrict__ lo) {
    int i = blockIdx.x * 256 + threadIdx.x;   // over 256*512
    if (i < 256 * 512) {
        int k = i / 512, c = i % 512;
        float v = W[i];
        bf16_t h = (bf16_t)v;
        float r = v - (float)h;
        hi[c * 256 + k] = h;
        lo[c * 256 + k] = (bf16_t)r;
    }
}

// ---------------- persistent dense transform: Y = [relu](X @ W [+ b]) ----------------

template <int CIN, int COUT, int RPT, bool PR, typename InT = float, typename OutT = float>
__global__ __launch_bounds__(256) void transform_persist(const InT* __restrict__ X,
                                                         const float* __restrict__ W,
                                                         const float* __restrict__ bias,
                                                         OutT* __restrict__ Y, int N) {
    constexpr int RT = RPT * COUT / 256;
    __shared__ float Ws[CIN * COUT];
    __shared__ float ps[RPT * CIN];
    int t = threadIdx.x;
    for (int i = t; i < CIN * COUT; i += 256) Ws[i] = W[i];

    int j = t % COUT;
    int lb = (t / COUT) * RT;
    float bv = 0.f;
    if constexpr (PR) bv = bias[j];

    int ntiles = (N + RPT - 1) / RPT;
    for (int tile = blockIdx.x; tile < ntiles; tile += gridDim.x) {
        int row0 = tile * RPT;
        __syncthreads();
        for (int i = t; i < RPT * CIN; i += 256) {
            int r = row0 + i / CIN;
            ps[i] = (r < N) ? (float)X[r * CIN + (i % CIN)] : 0.f;
        }
        __syncthreads();

        float acc[RT];
        #pragma unroll
        for (int r = 0; r < RT; ++r) acc[r] = bv;
        #pragma unroll
        for (int k = 0; k < CIN; ++k) {
            float w = Ws[k * COUT + j];
            #pragma unroll
            for (int r = 0; r < RT; ++r) acc[r] += ps[(lb + r) * CIN + k] * w;
        }
        #pragma unroll
        for (int r = 0; r < RT; ++r) {
            int row = row0 + lb + r;
            if (row < N) {
                float v = acc[r];
                if constexpr (PR) v = fmaxf(v, 0.f);
                Y[row * COUT + j] = (OutT)v;
            }
        }
    }
}

// ---------------- propagation (generic dtype): xout = Ahat xin [+bias, relu] ----------------

template <int C, bool PR, typename InT = float, typename OutT = float>
__global__ void propagate_kernel(const InT* __restrict__ xin, OutT* __restrict__ xout,
                                 const int* __restrict__ row_ptr, const int* __restrict__ col,
                                 const float* __restrict__ ew, const float* __restrict__ dinv,
                                 const float* __restrict__ bias, int N) {
    constexpr int NPB = 256 / C;
    int t = threadIdx.x;
    int node = blockIdx.x * NPB + t / C;
    int ch = t % C;
    if (node >= N) return;
    float di = dinv[node];
    float acc = (float)xin[node * C + ch] * di * di;
    int e0 = row_ptr[node], e1 = row_ptr[node + 1];
    for (int e = e0; e < e1; ++e) {
        acc += (float)xin[col[e] * C + ch] * ew[e];
    }
    if constexpr (PR) acc = fmaxf(acc + bias[ch], 0.f);
    xout[node * C + ch] = (OutT)acc;
}

// ---------------- propagation bf16, C=256: 1 node per wave, 4 ch/lane ----------------

__global__ __launch_bounds__(256) void propagate256_bf16(
    const bf16_t* __restrict__ xin, bf16_t* __restrict__ xout,
    const int* __restrict__ row_ptr, const int* __restrict__ col,
    const float* __restrict__ ew, const float* __restrict__ dinv, int N)
{
    int t = threadIdx.x;
    int node = blockIdx.x * 4 + (t >> 6);
    if (node >= N) return;
    int lane = t & 63;
    size_t base = (size_t)node * 256 + lane * 4;
    float di = dinv[node];
    float sn = di * di;
    bf16x4_t sv = *reinterpret_cast<const bf16x4_t*>(&xin[base]);
    float a0 = (float)sv[0] * sn, a1 = (float)sv[1] * sn;
    float a2 = (float)sv[2] * sn, a3 = (float)sv[3] * sn;
    int e0 = row_ptr[node], e1 = row_ptr[node + 1];
    for (int e = e0; e < e1; ++e) {
        int s = col[e];
        float w = ew[e];
        bf16x4_t v = *reinterpret_cast<const bf16x4_t*>(&xin[(size_t)s * 256 + lane * 4]);
        a0 += w * (float)v[0]; a1 += w * (float)v[1];
        a2 += w * (float)v[2]; a3 += w * (float)v[3];
    }
    bf16x4_t o;
    o[0] = (bf16_t)a0; o[1] = (bf16_t)a1; o[2] = (bf16_t)a2; o[3] = (bf16_t)a3;
    *reinterpret_cast<bf16x4_t*>(&xout[base]) = o;
}

// ---------------- L5: MFMA GEMM (N,256)x(256,512) bf16 + bias + relu + fused mean-pool ----
// A bf16 [N][256]; W split hi/lo bf16 in B^T layout [512][256]. 128x64 tile/block, 4 waves,
// wave = 32 rows x 64 cols = 2x4 frags of 16x16x32. No LDS in main loop (L2-broadcast W).

__global__ __launch_bounds__(256) void gemm5_pool_mfma(
    const bf16_t* __restrict__ A, const bf16_t* __restrict__ Wth,
    const bf16_t* __restrict__ Wtl, const float* __restrict__ bias,
    const int* __restrict__ batch, float* __restrict__ out, int N)
{
    __shared__ float red[64];
    int t = threadIdx.x;
    int wave = t >> 6, lane = t & 63;
    int lr = lane & 15, kg = lane >> 4;
    int brow = blockIdx.x * 128;
    int row0 = brow + wave * 32;
    int col0 = blockIdx.y * 64;

    f32x4_t acc[2][4];
    #pragma unroll
    for (int i = 0; i < 2; ++i)
        #pragma unroll
        for (int j = 0; j < 4; ++j) {
            f32x4_t z = {0.f, 0.f, 0.f, 0.f};
            acc[i][j] = z;
        }

    int ra = row0 + lr;      if (ra > N - 1) ra = N - 1;
    int rb = row0 + 16 + lr; if (rb > N - 1) rb = N - 1;
    const bf16_t* pa = A + (size_t)ra * 256 + kg * 8;
    const bf16_t* pb = A + (size_t)rb * 256 + kg * 8;

    #pragma unroll
    for (int kc = 0; kc < 256; kc += 32) {
        bf16x8_t a0 = *reinterpret_cast<const bf16x8_t*>(pa + kc);
        bf16x8_t a1 = *reinterpret_cast<const bf16x8_t*>(pb + kc);
        #pragma unroll
        for (int cf = 0; cf < 4; ++cf) {
            size_t bo = (size_t)(col0 + cf * 16 + lr) * 256 + kc + kg * 8;
            bf16x8_t bh = *reinterpret_cast<const bf16x8_t*>(&Wth[bo]);
            bf16x8_t bl = *reinterpret_cast<const bf16x8_t*>(&Wtl[bo]);
            acc[0][cf] = __builtin_amdgcn_mfma_f32_16x16x32_bf16(a0, bh, acc[0][cf], 0, 0, 0);
            acc[0][cf] = __builtin_amdgcn_mfma_f32_16x16x32_bf16(a0, bl, acc[0][cf], 0, 0, 0);
            acc[1][cf] = __builtin_amdgcn_mfma_f32_16x16x32_bf16(a1, bh, acc[1][cf], 0, 0, 0);
            acc[1][cf] = __builtin_amdgcn_mfma_f32_16x16x32_bf16(a1, bl, acc[1][cf], 0, 0, 0);
        }
    }

    // bias + relu. C/D layout: col = col0+cf*16+lr, row = row0+rf*16+kg*4+g
    float bv[4];
    #pragma unroll
    for (int cf = 0; cf < 4; ++cf) bv[cf] = bias[col0 + cf * 16 + lr];
    float v[2][4][4];
    #pragma unroll
    for (int rf = 0; rf < 2; ++rf)
        #pragma unroll
        for (int cf = 0; cf < 4; ++cf)
            #pragma unroll
            for (int g = 0; g < 4; ++g)
                v[rf][cf][g] = fmaxf(acc[rf][cf][g] + bv[cf], 0.f);

    int rlast = brow + 127; if (rlast > N - 1) rlast = N - 1;
    int b0 = batch[brow];
    if (b0 == batch[rlast]) {          // block-uniform branch
        if (t < 64) red[t] = 0.f;
        __syncthreads();
        #pragma unroll
        for (int cf = 0; cf < 4; ++cf) {
            float s = 0.f;
            #pragma unroll
            for (int rf = 0; rf < 2; ++rf)
                #pragma unroll
                for (int g = 0; g < 4; ++g) {
                    int r = row0 + rf * 16 + kg * 4 + g;
                    s += (r < N) ? v[rf][cf][g] : 0.f;
                }
            s += __shfl_xor(s, 16, 64);
            s += __shfl_xor(s, 32, 64);
            if (lane < 16) atomicAdd(&red[cf * 16 + lr], s);
        }
        __syncthreads();
        if (t < 64) atomicAdd(&out[(size_t)b0 * 512 + col0 + t], red[t]);
    } else {
        #pragma unroll
        for (int rf = 0; rf < 2; ++rf)
            #pragma unroll
            for (int g = 0; g < 4; ++g) {
                int r = row0 + rf * 16 + kg * 4 + g;
                if (r < N) {
                    int bb = batch[r];
                    #pragma unroll
                    for (int cf = 0; cf < 4; ++cf)
                        atomicAdd(&out[(size_t)bb * 512 + col0 + cf * 16 + lr], v[rf][cf][g]);
                }
            }
    }
}

__global__ void divide_kernel(float* __restrict__ out, const int* __restrict__ start, int total) {
    int i = blockIdx.x * 256 + threadIdx.x;
    if (i < total) {
        int g = i >> 9;
        float c = (float)(start[g + 1] - start[g]);
        out[i] /= fmaxf(c, 1.f);
    }
}

// ---------------- launch ----------------

extern "C" void kernel_launch(void* const* d_in, const int* in_sizes, int n_in,
                              void* d_out, int out_size, void* d_ws, size_t ws_size,
                              hipStream_t stream) {
    const float* x   = (const float*)d_in[0];
    const int* ei    = (const int*)d_in[1];
    const int* batch = (const int*)d_in[2];
    const float* W1 = (const float*)d_in[3];  const float* b1 = (const float*)d_in[4];
    const float* W2 = (const float*)d_in[5];  const float* b2 = (const float*)d_in[6];
    const float* W3 = (const float*)d_in[7];  const float* b3 = (const float*)d_in[8];
    const float* W4 = (const float*)d_in[9];  const float* b4 = (const float*)d_in[10];
    const float* W5 = (const float*)d_in[11]; const float* b5 = (const float*)d_in[12];
    float* out = (float*)d_out;

    const int N = NNODES, E = NEDGES;
    const int* src = ei;
    const int* dst = ei + E;

    char* ws = (char*)d_ws;
    size_t off = 0;
    auto alloc = [&](size_t bytes) {
        void* p = ws + off;
        off += (bytes + 255) & ~size_t(255);
        return p;
    };
    float* bufA   = (float*)alloc(sizeof(float) * size_t(N) * 256);
    float* bufB   = (float*)alloc(sizeof(float) * size_t(N) * 256);
    int* cnt      = (int*)alloc(sizeof(int) * N);
    int* fill     = (int*)alloc(sizeof(int) * N);
    int* row_ptr  = (int*)alloc(sizeof(int) * (N + 1));
    int* col      = (int*)alloc(sizeof(int) * E);
    float* ew     = (float*)alloc(sizeof(float) * E);
    float* dinv   = (float*)alloc(sizeof(float) * N);
    int* gstart   = (int*)alloc(sizeof(int) * (NGRAPH + 1));
    int* pre      = (int*)alloc(sizeof(int) * N);
    int* bsum     = (int*)alloc(sizeof(int) * 256);
    bf16_t* wt_hi = (bf16_t*)alloc(sizeof(bf16_t) * 512 * 256);
    bf16_t* wt_lo = (bf16_t*)alloc(sizeof(bf16_t) * 512 * 256);

    hipMemsetAsync(cnt, 0, sizeof(int) * N, stream);
    hipMemsetAsync(fill, 0, sizeof(int) * N, stream);
    hipMemsetAsync(out, 0, sizeof(float) * out_size, stream);

    count_kernel<<<(E + 255) / 256, 256, 0, stream>>>(dst, cnt, E);
    dinv_kernel<<<(N + 255) / 256, 256, 0, stream>>>(cnt, dinv, N);
    int nb = (N + 255) / 256;   // 196
    scan_part<<<nb, 256, 0, stream>>>(cnt, bsum, pre, N);
    scan_bsum<<<1, 256, 0, stream>>>(bsum, nb);
    scan_final<<<nb, 256, 0, stream>>>(pre, bsum, row_ptr, N);
    fill_kernel<<<(E + 255) / 256, 256, 0, stream>>>(src, dst, row_ptr, fill, dinv, col, ew, E);
    graph_starts<<<nb, 256, 0, stream>>>(batch, gstart, N);
    prep_w5<<<(256 * 512 + 255) / 256, 256, 0, stream>>>(W5, wt_hi, wt_lo);

    // L1: transform-first (32 -> 8), then propagate (+b1, relu)
    transform_persist<32, 8, 32, false><<<1024, 256, 0, stream>>>(x, W1, nullptr, bufA, N);
    propagate_kernel<8, true><<<(N + 31) / 32, 256, 0, stream>>>(bufA, bufB, row_ptr, col, ew, dinv, b1, N);

    // L2: propagate-first (8), then transform 8->16
    propagate_kernel<8, false><<<(N + 31) / 32, 256, 0, stream>>>(bufB, bufA, row_ptr, col, ew, dinv, nullptr, N);
    transform_persist<8, 16, 32, true><<<1024, 256, 0, stream>>>(bufA, W2, b2, bufB, N);

    // L3: propagate (16), transform 16->64 with bf16 output
    propagate_kernel<16, false><<<(N + 15) / 16, 256, 0, stream>>>(bufB, bufA, row_ptr, col, ew, dinv, nullptr, N);
    bf16_t* h3b = (bf16_t*)bufB;
    transform_persist<16, 64, 16, true, float, bf16_t><<<1024, 256, 0, stream>>>(bufA, W3, b3, h3b, N);

    // L4: propagate bf16 (64), transform 64->256 bf16->bf16
    bf16_t* h4a = (bf16_t*)bufA;
    propagate_kernel<64, false, bf16_t, bf16_t><<<(N + 3) / 4, 256, 0, stream>>>(h3b, h4a, row_ptr, col, ew, dinv, nullptr, N);
    bf16_t* h4b = (bf16_t*)bufB;
    transform_persist<64, 256, 8, true, bf16_t, bf16_t><<<512, 256, 0, stream>>>(h4a, W4, b4, h4b, N);

    // L5: propagate bf16 (256), then MFMA GEMM + bias + relu + fused mean-pool
    bf16_t* h5in = (bf16_t*)bufA;
    propagate256_bf16<<<(N + 3) / 4, 256, 0, stream>>>(h4b, h5in, row_ptr, col, ew, dinv, N);
    dim3 g5((N + 127) / 128, 8);
    gemm5_pool_mfma<<<g5, 256, 0, stream>>>(h5in, wt_hi, wt_lo, b5, batch, out, N);
    divide_kernel<<<(NGRAPH * 512 + 255) / 256, 256, 0, stream>>>(out, gstart, NGRAPH * 512);
}